// Round 7
// baseline (337.856 us; speedup 1.0000x reference)
//
#include <hip/hip_runtime.h>
#include <hip/hip_bf16.h>
#include <stdint.h>

typedef unsigned short u16;
typedef __bf16 bf16x8 __attribute__((ext_vector_type(8)));
typedef float f32x4 __attribute__((ext_vector_type(4)));

#define S_LEN 2048
#define BATCH 2
#define NHEADS 16
#define NGROUPS 4
#define DHEAD 128
#define QKV_W 3072   // fused projection width: 2048 q + 1024 kv

__device__ __forceinline__ float bf2f(u16 u) {
  union { uint32_t i; float f; } v; v.i = ((uint32_t)u) << 16; return v.f;
}
__device__ __forceinline__ u16 f2bf(float f) {
  union { float f; uint32_t i; } v; v.f = f;
  uint32_t r = v.i + 0x7FFF + ((v.i >> 16) & 1);
  return (u16)(r >> 16);
}
__device__ __forceinline__ void llds16(const void* g, void* l) {
  __builtin_amdgcn_global_load_lds(
      (const __attribute__((address_space(1))) uint32_t*)g,
      (__attribute__((address_space(3))) uint32_t*)l, 16, 0, 0);
}

__device__ __forceinline__ void store_out(u16* C, long i, float v) { C[i] = f2bf(v); }
__device__ __forceinline__ void store_out(float* C, long i, float v) { C[i] = v; }

// ============ prep_all: fp32->bf16 cvt of x + 3 weight transposes ============
// grid (64, 64, 5), block 256.
//  z=0: wq  (2048x2048) -> wqkvT[0:2048]
//  z=1: wkv (2048x1024) -> wqkvT[2048:3072]   (only bx<32 active)
//  z=2: wd  (2048x2048) -> wdT
//  z=3,4: cvt x -> xb (each slice 4096 blocks x 1024 elems)
__global__ void prep_all(const float* __restrict__ x,
                         const float* __restrict__ wq,
                         const float* __restrict__ wkv,
                         const float* __restrict__ wd,
                         u16* __restrict__ xb,
                         u16* __restrict__ wqkvT,
                         u16* __restrict__ wdT) {
  const int z = blockIdx.z;
  if (z >= 3) {
    long base = ((long)(z - 3) * 4096 + blockIdx.y * 64 + blockIdx.x) * 1024 +
                threadIdx.x * 4;
    float4 v = *(const float4*)(x + base);
    ushort4 o;
    o.x = f2bf(v.x); o.y = f2bf(v.y); o.z = f2bf(v.z); o.w = f2bf(v.w);
    *(ushort4*)(xb + base) = o;
    return;
  }
  const float* in; u16* out; int R, C;
  if (z == 0)      { in = wq;  out = wqkvT;                       R = 2048; C = 2048; }
  else if (z == 1) { if (blockIdx.x >= 32) return;
                     in = wkv; out = wqkvT + (long)2048 * 2048;   R = 2048; C = 1024; }
  else             { in = wd;  out = wdT;                         R = 2048; C = 2048; }

  __shared__ u16 tile[32][33];
  int tx = threadIdx.x & 31, ty = threadIdx.x >> 5;   // 32 x 8
  int c0 = blockIdx.x * 32, r0 = blockIdx.y * 32;
  for (int i = 0; i < 32; i += 8)
    tile[ty + i][tx] = f2bf(in[(long)(r0 + ty + i) * C + c0 + tx]);
  __syncthreads();
  for (int i = 0; i < 32; i += 8)
    out[(long)(c0 + ty + i) * R + r0 + tx] = tile[tx][ty + i];
}

// ============ prep_qkv: rope-Q (in place) + rope-K -> Kb + V-trans -> Vt =====
// 1-D grid 22528 blocks, block 256.
//  [0,16384)      rope on qkv cols [0,2048)
//  [16384,20480)  rope on qkv cols [2048,2560) -> Kb (B,4,S,128)
//  [20480,22528)  transpose qkv cols [2560,3072) -> Vt (B,4,128,S)
__global__ void prep_qkv(u16* __restrict__ qkv, u16* __restrict__ Kb,
                         u16* __restrict__ Vt) {
  const int bid = blockIdx.x;
  const int tid = threadIdx.x;
  if (bid < 16384) {           // rope Q
    long i = (long)bid * 256 + tid;
    int j = i & 63;
    long rest = i >> 6;
    int h = rest & 15;
    long bs = rest >> 4;
    int s = bs & (S_LEN - 1);
    float inv = exp2f(-(float)j * 0.20762050593045983f);
    float sv, cv;
    sincosf((float)s * inv, &sv, &cv);
    long base = bs * QKV_W + h * DHEAD + j;
    float x1 = bf2f(qkv[base]), x2 = bf2f(qkv[base + 64]);
    qkv[base] = f2bf(x1 * cv - x2 * sv);
    qkv[base + 64] = f2bf(x2 * cv + x1 * sv);
    return;
  }
  if (bid < 20480) {           // rope K -> Kb
    long i = (long)(bid - 16384) * 256 + tid;
    int j = i & 63;
    long rest = i >> 6;
    int g = rest & 3;
    long bs = rest >> 2;
    int s = bs & (S_LEN - 1);
    int b = (int)(bs >> 11);
    float inv = exp2f(-(float)j * 0.20762050593045983f);
    float sv, cv;
    sincosf((float)s * inv, &sv, &cv);
    long src = bs * QKV_W + 2048 + g * 128 + j;
    float x1 = bf2f(qkv[src]), x2 = bf2f(qkv[src + 64]);
    long dst = ((long)(b * NGROUPS + g) * S_LEN + s) * DHEAD + j;
    Kb[dst] = f2bf(x1 * cv - x2 * sv);
    Kb[dst + 64] = f2bf(x2 * cv + x1 * sv);
    return;
  }
  // V transpose
  int vb = bid - 20480;        // < 2048 : (64 s-tiles, 4 d-tiles, 8 bg)
  int sx = vb & 63, dy = (vb >> 6) & 3, bg = vb >> 8;
  int b = bg >> 2, g = bg & 3;
  __shared__ u16 tile[32][33];
  int tx = tid & 31, ty = tid >> 5;
  int s0 = sx * 32, d0 = dy * 32;
  for (int i = 0; i < 32; i += 8) {
    long s = s0 + ty + i;
    tile[ty + i][tx] = qkv[((long)b * S_LEN + s) * QKV_W + 2560 + g * 128 + d0 + tx];
  }
  __syncthreads();
  for (int i = 0; i < 32; i += 8) {
    int d = d0 + ty + i;
    Vt[((long)(b * NGROUPS + g) * DHEAD + d) * S_LEN + s0 + tx] = tile[tx][ty + i];
  }
}

// ============ GEMM C = A * B^T, tile 128x64, wave-tile 64x32 ================
// A: M x K row-major, Bt: N x K row-major, C: M x N row-major.
// 256 threads = 4 waves; grid (N/64, M/128). High waves/CU (6 blocks/CU
// at VGPR<=85) to hide the latency-structural K-iter period.
template <typename OutT>
__global__ __launch_bounds__(256, 6) void gemm_bt(
    const u16* __restrict__ A, const u16* __restrict__ Bt, OutT* __restrict__ C,
    int M, int N, int K) {
  __shared__ __align__(16) __bf16 As[128 * 32];   // 8 KB
  __shared__ __align__(16) __bf16 Bs[64 * 32];    // 4 KB
  const int tid = threadIdx.x;
  const int wv = tid >> 6;
  const int lane = tid & 63;
  const int quad = lane >> 4;
  const int l16 = lane & 15;
  const int bm = blockIdx.y * 128;
  const int bn = blockIdx.x * 64;

  f32x4 acc[4][2] = {};

  const int arow = tid >> 2;        // 0..63
  const int kseg = (tid & 3) * 8;
  const int wm = (wv & 1) * 64, wn = (wv >> 1) * 32;

  const u16* Ab = A + (long)(bm + arow) * K + kseg;
  const u16* Bb = Bt + (long)(bn + arow) * K + kseg;

  for (int k0 = 0; k0 < K; k0 += 32) {
    __syncthreads();
    llds16(Ab + k0, &As[arow * 32 + kseg]);
    llds16(Ab + (long)64 * K + k0, &As[(arow + 64) * 32 + kseg]);
    llds16(Bb + k0, &Bs[arow * 32 + kseg]);
    __syncthreads();

    bf16x8 af[4], bfr[2];
#pragma unroll
    for (int mt = 0; mt < 4; ++mt)
      af[mt] = *(const bf16x8*)&As[(wm + mt * 16 + l16) * 32 + quad * 8];
#pragma unroll
    for (int nt = 0; nt < 2; ++nt)
      bfr[nt] = *(const bf16x8*)&Bs[(wn + nt * 16 + l16) * 32 + quad * 8];
#pragma unroll
    for (int mt = 0; mt < 4; ++mt)
#pragma unroll
      for (int nt = 0; nt < 2; ++nt)
        acc[mt][nt] = __builtin_amdgcn_mfma_f32_16x16x32_bf16(
            af[mt], bfr[nt], acc[mt][nt], 0, 0, 0);
  }

#pragma unroll
  for (int mt = 0; mt < 4; ++mt)
#pragma unroll
    for (int nt = 0; nt < 2; ++nt)
#pragma unroll
      for (int r = 0; r < 4; ++r) {
        int row = bm + wm + mt * 16 + quad * 4 + r;
        int col = bn + wn + nt * 16 + l16;
        store_out(C, (long)row * N + col, acc[mt][nt][r]);
      }
}

// ---------------- Flash attention v5: 64-key chunks, paired tiles ----------
// grid: (16, NHEADS, B) = 512 blocks -> 2/CU; each block runs tiles t and
// 31-t sequentially => uniform 33 chunk64s/block (flat concurrency).
__global__ __launch_bounds__(256, 2) void attn_k5(
    const u16* __restrict__ Q,   // qkv (B,S,3072), cols [0,2048) post-rope
    const u16* __restrict__ Kb,  // (B,4,S,128)  post-rope
    const u16* __restrict__ Vt,  // (B,4,128,S)
    u16* __restrict__ ctx) {     // (B,S,16,128)
  __shared__ __align__(16) __bf16 Ks[2][64 * 128];   // 32 KB
  __shared__ __align__(16) __bf16 Vts[2][128 * 64];  // 32 KB
  __shared__ __align__(16) __bf16 Ps[64 * 64];       // 8 KB

  const int h = blockIdx.y, b = blockIdx.z, g = h >> 2;
  const int tid = threadIdx.x, wv = tid >> 6, lane = tid & 63;
  const int quad = lane >> 4, l16 = lane & 15;
  const float SCALE = 0.08838834764831845f;

  const long kbase = (long)(b * NGROUPS + g) * S_LEN * DHEAD;
  const long vbase = (long)(b * NGROUPS + g) * DHEAD * S_LEN;

  const int krow_off = lane >> 4;
  const int vrow_off = lane >> 3;

  const __bf16 oneb = (__bf16)((l16 == 0) ? 1.0f : 0.0f);
  const bf16x8 bones = {oneb, oneb, oneb, oneb, oneb, oneb, oneb, oneb};

  for (int pass = 0; pass < 2; ++pass) {
    const int tile = pass == 0 ? (int)blockIdx.x : 31 - (int)blockIdx.x;
    const int q0 = tile * 64;
    const int nch = tile + 1;   // 64-key chunks

    bf16x8 aq[4];
    {
      const u16* qp = Q + (long)(b * S_LEN + q0 + wv * 16 + l16) * QKV_W + h * DHEAD + quad * 8;
#pragma unroll
      for (int ds = 0; ds < 4; ++ds)
        aq[ds] = *(const bf16x8*)(qp + ds * 32);
    }

#pragma unroll
    for (int i = 0; i < 4; ++i) {
      int r0 = wv * 16 + i * 4;
      int row = r0 + krow_off;
      int c = l16 ^ (row & 15);
      llds16(Kb + kbase + (long)row * DHEAD + c * 8, &Ks[0][r0 * 128 + lane * 8]);
    }
#pragma unroll
    for (int i = 0; i < 4; ++i) {
      int d0 = wv * 32 + i * 8;
      int row = d0 + vrow_off;
      int c = (lane & 7) ^ (row & 7);
      llds16(Vt + vbase + (long)row * S_LEN + c * 8, &Vts[0][d0 * 64 + lane * 8]);
    }
    __syncthreads();

    f32x4 Oacc[9] = {};

    for (int kc = 0; kc < nch; ++kc) {
      const int cur = kc & 1;
      if (kc + 1 < nch) {
        const int nxt = cur ^ 1;
#pragma unroll
        for (int i = 0; i < 4; ++i) {
          int r0 = wv * 16 + i * 4;
          int row = r0 + krow_off;
          int c = l16 ^ (row & 15);
          llds16(Kb + kbase + (long)((kc + 1) * 64 + row) * DHEAD + c * 8,
                 &Ks[nxt][r0 * 128 + lane * 8]);
        }
#pragma unroll
        for (int i = 0; i < 4; ++i) {
          int d0 = wv * 32 + i * 8;
          int row = d0 + vrow_off;
          int c = (lane & 7) ^ (row & 7);
          llds16(Vt + vbase + (long)row * S_LEN + (kc + 1) * 64 + c * 8,
                 &Vts[nxt][d0 * 64 + lane * 8]);
        }
      }

      // QK^T : 16q x 64k per wave (16 MFMA)
      f32x4 sacc[4] = {};
#pragma unroll
      for (int ds = 0; ds < 4; ++ds) {
        int pos0 = ((ds * 4 + quad) ^ l16) * 8;
#pragma unroll
        for (int nt = 0; nt < 4; ++nt) {
          bf16x8 bk = *(const bf16x8*)&Ks[cur][(nt * 16 + l16) * 128 + pos0];
          sacc[nt] = __builtin_amdgcn_mfma_f32_16x16x32_bf16(aq[ds], bk, sacc[nt], 0, 0, 0);
        }
      }

      // no-max softmax: p = exp(score*scale), masked to 0; write P (xor8)
#pragma unroll
      for (int nt = 0; nt < 4; ++nt)
#pragma unroll
        for (int r = 0; r < 4; ++r) {
          int qrow = q0 + wv * 16 + quad * 4 + r;
          int key = kc * 64 + nt * 16 + l16;
          float p = (key <= qrow) ? __expf(sacc[nt][r] * SCALE) : 0.f;
          int qlocal = quad * 4 + r;
          int chunk = nt * 2 + (l16 >> 3);
          int pos = chunk ^ (qlocal & 7);
          Ps[(wv * 16 + qlocal) * 64 + pos * 8 + (l16 & 7)] = (__bf16)p;
        }

      // PV (+ ones-column row-sum into Oacc[8]): 18 MFMA
      bf16x8 ap[2];
#pragma unroll
      for (int kf = 0; kf < 2; ++kf) {
        int pos = ((kf * 4 + quad) ^ (l16 & 7)) * 8;
        ap[kf] = *(const bf16x8*)&Ps[(wv * 16 + l16) * 64 + pos];
      }
#pragma unroll
      for (int nt = 0; nt < 8; ++nt)
#pragma unroll
        for (int kf = 0; kf < 2; ++kf) {
          int pos = ((kf * 4 + quad) ^ (l16 & 7)) * 8;
          bf16x8 bv = *(const bf16x8*)&Vts[cur][(nt * 16 + l16) * 64 + pos];
          Oacc[nt] = __builtin_amdgcn_mfma_f32_16x16x32_bf16(ap[kf], bv, Oacc[nt], 0, 0, 0);
        }
      Oacc[8] = __builtin_amdgcn_mfma_f32_16x16x32_bf16(ap[0], bones, Oacc[8], 0, 0, 0);
      Oacc[8] = __builtin_amdgcn_mfma_f32_16x16x32_bf16(ap[1], bones, Oacc[8], 0, 0, 0);

      __syncthreads();
    }

    float lsum[4];
#pragma unroll
    for (int r = 0; r < 4; ++r)
      lsum[r] = __shfl(Oacc[8][r], quad << 4, 64);

    const long obase = ((long)(b * S_LEN + q0 + wv * 16) * NHEADS + h) * DHEAD;
#pragma unroll
    for (int nt = 0; nt < 8; ++nt)
#pragma unroll
      for (int r = 0; r < 4; ++r) {
        int lrow = quad * 4 + r;
        ctx[obase + (long)lrow * NHEADS * DHEAD + nt * 16 + l16] =
            f2bf(Oacc[nt][r] / lsum[r]);
      }
  }
}

extern "C" void kernel_launch(void* const* d_in, const int* in_sizes, int n_in,
                              void* d_out, int out_size, void* d_ws, size_t ws_size,
                              hipStream_t stream) {
  const float* x   = (const float*)d_in[0];   // (B,S,2048) fp32
  const float* wq  = (const float*)d_in[1];   // (2048, 2048) fp32
  const float* wkv = (const float*)d_in[2];   // (2048, 1024) fp32
  const float* wd  = (const float*)d_in[3];   // (2048, 2048) fp32
  float* out = (float*)d_out;                 // (B,S,2048) fp32

  char* ws = (char*)d_ws;
  u16* wqkvT = (u16*)(ws + 1048576);           // 12582912 B (3072 x 2048 bf16)
  u16* wdT   = (u16*)(ws + 13631488);          //  8388608 B (2048 x 2048 bf16)
  u16* xb    = (u16*)(ws + 22020096);          // 16777216 B (B*S, 2048) bf16
  u16* qkv   = (u16*)(ws + 38797312);          // 25165824 B (B*S, 3072) bf16
  u16* Kb    = (u16*)(ws + 63963136);          //  4194304 B (B,4,S,128) bf16
  u16* Vt    = (u16*)(ws + 68157440);          //  4194304 B (B,4,128,S) bf16
  u16* ctx   = (u16*)(ws + 72351744);          // 16777216 B (B,S,16,128) bf16
                                               // total 89128960 B

  prep_all<<<dim3(64, 64, 5), 256, 0, stream>>>(x, wq, wkv, wd, xb, wqkvT, wdT);

  // fused QKV projection: (B*S,2048) x (3072,2048)^T -> (B*S,3072)
  gemm_bt<u16><<<dim3(48, 32), 256, 0, stream>>>(xb, wqkvT, qkv, 4096, 3072, 2048);

  prep_qkv<<<22528, 256, 0, stream>>>(qkv, Kb, Vt);

  attn_k5<<<dim3(16, 16, 2), 256, 0, stream>>>(qkv, Kb, Vt, ctx);

  gemm_bt<float><<<dim3(32, 32), 256, 0, stream>>>(ctx, wdT, out, 4096, 2048, 2048);
}